// Round 3
// baseline (3999.233 us; speedup 1.0000x reference)
//
#include <hip/hip_runtime.h>
#include <hip/hip_bf16.h>
#include <math.h>

// Problem: B=4, T=2048, D=1024, H=16, DH=64.
// Inputs fp32, output fp32 (proven: R1 NaN + R2 finite-wrong pattern).
// Internal compute in bf16 (threshold 7.5e-2 licenses it).
// out = softmax_causal((xWq)(xWk)^T / 8) (xWv)  @ Wout

#define Bb 4
#define Tt 2048
#define Dd 1024
#define Hh 16
#define DH 64
#define Mrows (Bb*Tt)          // 8192
#define NEGBIG (-1.0e30f)

__device__ __forceinline__ float bf2f(unsigned short u) {
    union { unsigned int i; float f; } v; v.i = ((unsigned int)u) << 16; return v.f;
}
__device__ __forceinline__ unsigned short f2bf(float f) {
    union { float f; unsigned int i; } v; v.f = f;
    unsigned int x = v.i;
    unsigned int r = (x + 0x7fffu + ((x >> 16) & 1u)) >> 16;   // RNE
    return (unsigned short)r;
}

// ---------------------------------------------------------------------------
// Dtype sniff + convert to canonical bf16 (robust to fp32 OR bf16 source).
// fp32 source: even ushorts are mantissa-low-halves -> uniform exponent field.
// bf16 N(0,sigma) source: exponent always sane.
// ---------------------------------------------------------------------------
__global__ __launch_bounds__(256) void convert_to_bf16(const void* __restrict__ src,
                                                       unsigned short* __restrict__ dst,
                                                       long n) {
    const unsigned short* us = (const unsigned short*)src;
    int crazy = 0;
    #pragma unroll
    for (int j = 0; j < 32; ++j) {
        const unsigned short u = us[2 * j];
        const int e = (u >> 7) & 0xFF;
        if (e >= 191 || (e <= 64 && (u & 0x7FFFu) != 0)) ++crazy;
    }
    const bool is_f32 = (crazy >= 2);
    const long i0 = (long)blockIdx.x * (256 * 8) + threadIdx.x;
    if (is_f32) {
        const float* fs = (const float*)src;
        #pragma unroll
        for (int p = 0; p < 8; ++p) {
            const long i = i0 + (long)p * 256;
            if (i < n) dst[i] = f2bf(fs[i]);
        }
    } else {
        #pragma unroll
        for (int p = 0; p < 8; ++p) {
            const long i = i0 + (long)p * 256;
            if (i < n) dst[i] = us[i];
        }
    }
}

// ---------------------------------------------------------------------------
// GEMM1: qkv = x @ Wqkv  (M=8192, K=1024, N=3072), scatter to Q/K/V (B,H,T,DH)
// Q is pre-scaled by 1/8 (exact in bf16).
// ---------------------------------------------------------------------------
__global__ __launch_bounds__(256) void gemm_qkv(const unsigned short* __restrict__ X,
                                                const unsigned short* __restrict__ W,
                                                unsigned short* __restrict__ Qo,
                                                unsigned short* __restrict__ Ko,
                                                unsigned short* __restrict__ Vo) {
    __shared__ unsigned short As[16][64];
    __shared__ unsigned short Bs[16][64];
    const int tid = threadIdx.x;
    const int tx = tid & 15, ty = tid >> 4;
    const int m0 = blockIdx.y * 64;
    const int n0 = blockIdx.x * 64;
    float acc[4][4] = {};

    for (int k0 = 0; k0 < Dd; k0 += 16) {
        {
            const int kk = tid & 15;
            const int r  = tid >> 4;
            #pragma unroll
            for (int p = 0; p < 4; ++p) {
                const int row = r + p * 16;
                As[kk][row] = X[(size_t)(m0 + row) * Dd + k0 + kk];
            }
            const int nn = tid & 63;
            const int kb = tid >> 6;
            #pragma unroll
            for (int p = 0; p < 4; ++p) {
                const int kk2 = kb + p * 4;
                Bs[kk2][nn] = W[(size_t)(k0 + kk2) * (3 * Dd) + n0 + nn];
            }
        }
        __syncthreads();
        #pragma unroll
        for (int kk = 0; kk < 16; ++kk) {
            float a[4], b[4];
            #pragma unroll
            for (int i = 0; i < 4; ++i) a[i] = bf2f(As[kk][ty * 4 + i]);
            #pragma unroll
            for (int j = 0; j < 4; ++j) b[j] = bf2f(Bs[kk][tx * 4 + j]);
            #pragma unroll
            for (int i = 0; i < 4; ++i)
                #pragma unroll
                for (int j = 0; j < 4; ++j)
                    acc[i][j] = fmaf(a[i], b[j], acc[i][j]);
        }
        __syncthreads();
    }

    #pragma unroll
    for (int i = 0; i < 4; ++i) {
        const int m  = m0 + ty * 4 + i;
        const int bb = m >> 11;
        const int t  = m & 2047;
        #pragma unroll
        for (int j = 0; j < 4; ++j) {
            const int n   = n0 + tx * 4 + j;
            const int s   = n >> 10;          // 0=q 1=k 2=v
            const int rem = n & 1023;
            const int h   = rem >> 6;
            const int dh  = rem & 63;
            float v = acc[i][j];
            if (s == 0) v *= 0.125f;          // 1/sqrt(DH), exact in bf16
            const size_t idx = (((size_t)(bb * Hh + h)) * Tt + t) * DH + dh;
            unsigned short* dst = (s == 0) ? Qo : (s == 1 ? Ko : Vo);
            dst[idx] = f2bf(v);
        }
    }
}

// ---------------------------------------------------------------------------
// Flash attention: block = (b,h, 64-row q-tile).  Online softmax over causal
// 64-key tiles.  Finite sentinels (-1e30).  Writes (B,T,H,DH)=(B,T,D) bf16.
// ---------------------------------------------------------------------------
__global__ __launch_bounds__(256) void attn_flash(const unsigned short* __restrict__ Q,
                                                  const unsigned short* __restrict__ K,
                                                  const unsigned short* __restrict__ V,
                                                  unsigned short* __restrict__ AO) {
    const int qt = blockIdx.x;
    const int bh = blockIdx.y;
    const int b  = bh >> 4, h = bh & 15;
    const int tid = threadIdx.x;
    const int tx = tid & 15, ty = tid >> 4;
    const int q0 = qt * 64;
    const size_t base = (size_t)bh * Tt * DH;

    __shared__ unsigned short Qs[64][64];
    __shared__ unsigned short Ks[64][64];
    __shared__ unsigned short Vs[64][64];
    __shared__ float Ps[64][64];
    __shared__ float m_s[64], l_s[64];

    #pragma unroll
    for (int p = 0; p < 16; ++p) {
        const int idx = p * 256 + tid;
        const int r = idx >> 6, c = idx & 63;
        Qs[r][c] = Q[base + (size_t)(q0 + r) * DH + c];
    }
    if (tid < 64) { m_s[tid] = NEGBIG; l_s[tid] = 0.0f; }

    float O[4][4] = {};

    for (int j0 = 0; j0 <= q0; j0 += 64) {
        __syncthreads();
        #pragma unroll
        for (int p = 0; p < 16; ++p) {
            const int idx = p * 256 + tid;
            const int r = idx >> 6, c = idx & 63;
            Ks[r][c] = K[base + (size_t)(j0 + r) * DH + c];
            Vs[r][c] = V[base + (size_t)(j0 + r) * DH + c];
        }
        __syncthreads();

        float S[4][4] = {};
        for (int d = 0; d < 64; ++d) {
            float qv[4], kv[4];
            #pragma unroll
            for (int i = 0; i < 4; ++i) qv[i] = bf2f(Qs[ty * 4 + i][d]);
            #pragma unroll
            for (int j = 0; j < 4; ++j) kv[j] = bf2f(Ks[tx * 4 + j][d]);
            #pragma unroll
            for (int i = 0; i < 4; ++i)
                #pragma unroll
                for (int j = 0; j < 4; ++j)
                    S[i][j] = fmaf(qv[i], kv[j], S[i][j]);
        }
        if (j0 == q0) {
            #pragma unroll
            for (int i = 0; i < 4; ++i)
                #pragma unroll
                for (int j = 0; j < 4; ++j)
                    if (tx * 4 + j > ty * 4 + i) S[i][j] = NEGBIG;
        }

        float rmax[4], rsum[4], alpha[4], newm[4];
        #pragma unroll
        for (int i = 0; i < 4; ++i) {
            float mx = fmaxf(fmaxf(S[i][0], S[i][1]), fmaxf(S[i][2], S[i][3]));
            #pragma unroll
            for (int off = 1; off < 16; off <<= 1)
                mx = fmaxf(mx, __shfl_xor(mx, off, 64));
            rmax[i] = mx;
        }
        #pragma unroll
        for (int i = 0; i < 4; ++i) {
            const float mo = m_s[ty * 4 + i];
            newm[i]  = fmaxf(mo, rmax[i]);
            alpha[i] = __expf(mo - newm[i]);
        }
        #pragma unroll
        for (int i = 0; i < 4; ++i) {
            float s0 = 0.f;
            #pragma unroll
            for (int j = 0; j < 4; ++j) {
                const float p = __expf(S[i][j] - newm[i]);
                Ps[ty * 4 + i][tx * 4 + j] = p;
                s0 += p;
            }
            #pragma unroll
            for (int off = 1; off < 16; off <<= 1)
                s0 += __shfl_xor(s0, off, 64);
            rsum[i] = s0;
        }
        __syncthreads();
        if (tx == 0) {
            #pragma unroll
            for (int i = 0; i < 4; ++i) {
                const int r = ty * 4 + i;
                m_s[r] = newm[i];
                l_s[r] = l_s[r] * alpha[i] + rsum[i];
            }
        }
        #pragma unroll
        for (int i = 0; i < 4; ++i)
            #pragma unroll
            for (int j = 0; j < 4; ++j)
                O[i][j] *= alpha[i];
        for (int c = 0; c < 64; ++c) {
            float pv[4], vv[4];
            #pragma unroll
            for (int i = 0; i < 4; ++i) pv[i] = Ps[ty * 4 + i][c];
            #pragma unroll
            for (int j = 0; j < 4; ++j) vv[j] = bf2f(Vs[c][tx * 4 + j]);
            #pragma unroll
            for (int i = 0; i < 4; ++i)
                #pragma unroll
                for (int j = 0; j < 4; ++j)
                    O[i][j] = fmaf(pv[i], vv[j], O[i][j]);
        }
    }
    __syncthreads();

    #pragma unroll
    for (int i = 0; i < 4; ++i) {
        const int t = q0 + ty * 4 + i;
        const float inv_l = 1.0f / l_s[ty * 4 + i];
        #pragma unroll
        for (int j = 0; j < 4; ++j) {
            const int dh = tx * 4 + j;
            const size_t idx = (((size_t)b * Tt + t) * Hh + h) * DH + dh;
            AO[idx] = f2bf(O[i][j] * inv_l);
        }
    }
}

// ---------------------------------------------------------------------------
// GEMM2: out = attn_out(8192x1024) @ Wout(1024x1024), FP32 out.
// ---------------------------------------------------------------------------
__global__ __launch_bounds__(256) void gemm_out(const unsigned short* __restrict__ A,
                                                const unsigned short* __restrict__ W,
                                                float* __restrict__ Out) {
    __shared__ unsigned short As[16][64];
    __shared__ unsigned short Bs[16][64];
    const int tid = threadIdx.x;
    const int tx = tid & 15, ty = tid >> 4;
    const int m0 = blockIdx.y * 64;
    const int n0 = blockIdx.x * 64;
    float acc[4][4] = {};

    for (int k0 = 0; k0 < Dd; k0 += 16) {
        {
            const int kk = tid & 15;
            const int r  = tid >> 4;
            #pragma unroll
            for (int p = 0; p < 4; ++p) {
                const int row = r + p * 16;
                As[kk][row] = A[(size_t)(m0 + row) * Dd + k0 + kk];
            }
            const int nn = tid & 63;
            const int kb = tid >> 6;
            #pragma unroll
            for (int p = 0; p < 4; ++p) {
                const int kk2 = kb + p * 4;
                Bs[kk2][nn] = W[(size_t)(k0 + kk2) * Dd + n0 + nn];
            }
        }
        __syncthreads();
        #pragma unroll
        for (int kk = 0; kk < 16; ++kk) {
            float a[4], b[4];
            #pragma unroll
            for (int i = 0; i < 4; ++i) a[i] = bf2f(As[kk][ty * 4 + i]);
            #pragma unroll
            for (int j = 0; j < 4; ++j) b[j] = bf2f(Bs[kk][tx * 4 + j]);
            #pragma unroll
            for (int i = 0; i < 4; ++i)
                #pragma unroll
                for (int j = 0; j < 4; ++j)
                    acc[i][j] = fmaf(a[i], b[j], acc[i][j]);
        }
        __syncthreads();
    }

    #pragma unroll
    for (int i = 0; i < 4; ++i) {
        const int m = m0 + ty * 4 + i;
        #pragma unroll
        for (int j = 0; j < 4; ++j) {
            const int n = n0 + tx * 4 + j;
            Out[(size_t)m * Dd + n] = acc[i][j];     // FP32 store
        }
    }
}

// ---------------------------------------------------------------------------
extern "C" void kernel_launch(void* const* d_in, const int* in_sizes, int n_in,
                              void* d_out, int out_size, void* d_ws, size_t ws_size,
                              hipStream_t stream) {
    const void* x_raw    = d_in[0];
    // d_in[1] = causal mask (constant tril) — handled analytically, ignored.
    const void* Wqkv_raw = d_in[2];
    const void* Wout_raw = d_in[3];
    float* out = (float*)d_out;

    const size_t SZ = (size_t)Bb * Hh * Tt * DH;       // 8,388,608
    unsigned short* ws = (unsigned short*)d_ws;
    unsigned short* Qw     = ws;
    unsigned short* Kw     = ws + SZ;
    unsigned short* Vw     = ws + 2 * SZ;
    unsigned short* AO     = ws + 3 * SZ;              // (B,T,H,DH)=(B,T,D)
    unsigned short* Wqkv_b = ws + 4 * SZ;              // 3,145,728 elems
    unsigned short* Wout_b = Wqkv_b + (size_t)Dd * 3 * Dd;  // 1,048,576 elems
    // x_b scratch lives in d_out (33.5 MB fp32 buffer; x_b needs 16.8 MB).
    // Consumed by gemm_qkv before gemm_out overwrites d_out — stream-ordered.
    unsigned short* x_b    = (unsigned short*)d_out;

    const long nX = (long)Mrows * Dd;                  // 8,388,608
    const long nWq = (long)Dd * 3 * Dd;                // 3,145,728
    const long nWo = (long)Dd * Dd;                    // 1,048,576

    convert_to_bf16<<<dim3((nX  + 2047) / 2048), 256, 0, stream>>>(x_raw,    x_b,    nX);
    convert_to_bf16<<<dim3((nWq + 2047) / 2048), 256, 0, stream>>>(Wqkv_raw, Wqkv_b, nWq);
    convert_to_bf16<<<dim3((nWo + 2047) / 2048), 256, 0, stream>>>(Wout_raw, Wout_b, nWo);

    gemm_qkv  <<<dim3(3 * Dd / 64, Mrows / 64), 256, 0, stream>>>(x_b, Wqkv_b, Qw, Kw, Vw);
    attn_flash<<<dim3(Tt / 64, Bb * Hh),        256, 0, stream>>>(Qw, Kw, Vw, AO);
    gemm_out  <<<dim3(Dd / 64, Mrows / 64),     256, 0, stream>>>(AO, Wout_b, out);
}

// Round 4
// 464.747 us; speedup vs baseline: 8.6052x; 8.6052x over previous
//
#include <hip/hip_runtime.h>
#include <hip/hip_bf16.h>
#include <math.h>

// B=4, T=2048, D=1024, H=16, DH=64.  fp32 in / fp32 out, bf16 MFMA internal.
// out = softmax_causal((xWq)(xWk)^T / 8) (xWv) @ Wout

#define Bb 4
#define Tt 2048
#define Dd 1024
#define Hh 16
#define DH 64
#define Mrows (Bb*Tt)          // 8192
#define NEGBIG (-1.0e30f)

typedef unsigned short u16;
typedef __attribute__((ext_vector_type(8))) short bf16x8;
typedef __attribute__((ext_vector_type(4))) float f32x4;

__device__ __forceinline__ float bf2f(u16 u) {
    union { unsigned int i; float f; } v; v.i = ((unsigned int)u) << 16; return v.f;
}
__device__ __forceinline__ u16 f2bf(float f) {
    union { float f; unsigned int i; } v; v.f = f;
    unsigned int x = v.i;
    return (u16)((x + 0x7fffu + ((x >> 16) & 1u)) >> 16);      // RNE
}

typedef __attribute__((address_space(1))) const void glob_cv;
typedef __attribute__((address_space(3))) void lds_v;
__device__ __forceinline__ void gl2lds16(const void* g, void* l) {
    __builtin_amdgcn_global_load_lds((glob_cv*)g, (lds_v*)l, 16, 0, 0);
}

// ---------------------------------------------------------------------------
// fp32 -> bf16 straight convert (x).  8 elems/thread, 16B stores.
// ---------------------------------------------------------------------------
__global__ __launch_bounds__(256) void convert_x(const float* __restrict__ src,
                                                 u16* __restrict__ dst) {
    const long i = ((long)blockIdx.x * 256 + threadIdx.x) * 8;
    float4 f0 = *(const float4*)(src + i);
    float4 f1 = *(const float4*)(src + i + 4);
    union { u16 u[8]; uint4 v; } o;
    o.u[0] = f2bf(f0.x); o.u[1] = f2bf(f0.y); o.u[2] = f2bf(f0.z); o.u[3] = f2bf(f0.w);
    o.u[4] = f2bf(f1.x); o.u[5] = f2bf(f1.y); o.u[6] = f2bf(f1.z); o.u[7] = f2bf(f1.w);
    *(uint4*)(dst + i) = o.v;
}

// ---------------------------------------------------------------------------
// fp32 W[K][N] -> bf16 Wt[N][K]  (transpose via padded LDS tile, coalesced).
// ---------------------------------------------------------------------------
__global__ __launch_bounds__(256) void convert_transpose_w(const float* __restrict__ W,
                                                           u16* __restrict__ Wt,
                                                           int N, int K) {
    __shared__ u16 tile[64][65];
    const int n0 = blockIdx.x * 64, k0 = blockIdx.y * 64;
    const int c = threadIdx.x & 63, r4 = threadIdx.x >> 6;
    #pragma unroll
    for (int p = 0; p < 16; ++p) {
        const int r = p * 4 + r4;
        tile[r][c] = f2bf(W[(size_t)(k0 + r) * N + n0 + c]);
    }
    __syncthreads();
    #pragma unroll
    for (int p = 0; p < 16; ++p) {
        const int r = p * 4 + r4;     // n index
        Wt[(size_t)(n0 + r) * K + k0 + c] = tile[c][r];
    }
}

// ---------------------------------------------------------------------------
// V [bh][t][dh] -> Vt [bh][dh][t]
// ---------------------------------------------------------------------------
__global__ __launch_bounds__(256) void transpose_v(const u16* __restrict__ V,
                                                   u16* __restrict__ Vt) {
    __shared__ u16 tile[64][65];
    const int t0 = blockIdx.x * 64, bh = blockIdx.y;
    const size_t ib = (size_t)bh * Tt * DH, ob = (size_t)bh * DH * Tt;
    const int c = threadIdx.x & 63, r4 = threadIdx.x >> 6;
    #pragma unroll
    for (int p = 0; p < 16; ++p) {
        const int r = p * 4 + r4;
        tile[r][c] = V[ib + (size_t)(t0 + r) * DH + c];
    }
    __syncthreads();
    #pragma unroll
    for (int p = 0; p < 16; ++p) {
        const int r = p * 4 + r4;     // dh
        Vt[ob + (size_t)r * Tt + t0 + c] = tile[c][r];
    }
}

// ---------------------------------------------------------------------------
// MFMA GEMM: C[M][N] = A[M][K] * Bt[N][K]^T, K=1024, BK=32, 128x128 tile,
// 4 waves (2x2), each 4x4 MFMA 16x16x32 tiles.  LDS layout [kblk][row][8]
// (forced by global_load_lds wave-uniform-base; gives bank-spread b128 reads).
// MODE 0: scatter to Q(x0.125)/K/V (B,H,T,DH) bf16.  MODE 1: fp32 out.
// ---------------------------------------------------------------------------
template <int MODE>
__global__ __launch_bounds__(256) void gemm_mfma(const u16* __restrict__ A,
                                                 const u16* __restrict__ Bt,
                                                 u16* __restrict__ Qo,
                                                 u16* __restrict__ Ko,
                                                 u16* __restrict__ Vo,
                                                 float* __restrict__ Out) {
    __shared__ u16 As[4 * 128 * 8];      // [qb 0..3][row 0..127][8]
    __shared__ u16 Bs[4 * 128 * 8];
    const int tid  = threadIdx.x;
    const int lane = tid & 63, w = tid >> 6;
    const int ml   = lane & 15, q = lane >> 4;     // fragment row/col & quad
    const int wm   = w >> 1, wn = w & 1;
    const int m0 = blockIdx.y * 128, n0 = blockIdx.x * 128;

    f32x4 acc[4][4];
    #pragma unroll
    for (int i = 0; i < 4; ++i)
        #pragma unroll
        for (int j = 0; j < 4; ++j) acc[i][j] = (f32x4){0.f, 0.f, 0.f, 0.f};

    for (int k0 = 0; k0 < Dd; k0 += 32) {
        __syncthreads();
        #pragma unroll
        for (int it = 0; it < 2; ++it) {
            const int c = it * 256 + tid;          // chunk 0..511
            const int row = c & 127, qb = c >> 7;  // LDS off = c*16
            gl2lds16(A  + (size_t)(m0 + row) * Dd + k0 + qb * 8, (char*)As + c * 16);
            gl2lds16(Bt + (size_t)(n0 + row) * Dd + k0 + qb * 8, (char*)Bs + c * 16);
        }
        __syncthreads();

        bf16x8 af[4], bfr[4];
        #pragma unroll
        for (int i = 0; i < 4; ++i)
            af[i] = *(const bf16x8*)((const char*)As + (q * 128 + wm * 64 + i * 16 + ml) * 16);
        #pragma unroll
        for (int j = 0; j < 4; ++j)
            bfr[j] = *(const bf16x8*)((const char*)Bs + (q * 128 + wn * 64 + j * 16 + ml) * 16);
        #pragma unroll
        for (int i = 0; i < 4; ++i)
            #pragma unroll
            for (int j = 0; j < 4; ++j)
                acc[i][j] = __builtin_amdgcn_mfma_f32_16x16x32_bf16(af[i], bfr[j], acc[i][j], 0, 0, 0);
    }

    // epilogue: C/D layout col=lane&15, row=quad*4+reg
    #pragma unroll
    for (int i = 0; i < 4; ++i) {
        #pragma unroll
        for (int j = 0; j < 4; ++j) {
            #pragma unroll
            for (int r = 0; r < 4; ++r) {
                const int m = m0 + wm * 64 + i * 16 + q * 4 + r;
                const int n = n0 + wn * 64 + j * 16 + ml;
                if (MODE == 0) {
                    const int bb = m >> 11, t = m & 2047;
                    const int s = n >> 10, rem = n & 1023, h = rem >> 6, dh = rem & 63;
                    float v = acc[i][j][r];
                    if (s == 0) v *= 0.125f;       // 1/sqrt(DH)
                    u16* dst = (s == 0) ? Qo : (s == 1 ? Ko : Vo);
                    dst[(((size_t)(bb * Hh + h)) * Tt + t) * DH + dh] = f2bf(v);
                } else {
                    Out[(size_t)m * Dd + n] = acc[i][j][r];
                }
            }
        }
    }
}

// ---------------------------------------------------------------------------
// MFMA flash attention.  Block: 64 Q-rows (4 waves x 16 rows), K-tiles of 64.
// m/l/O in registers (wave-private rows).  P via wave-private padded LDS.
// ---------------------------------------------------------------------------
__global__ __launch_bounds__(256) void attn_mfma(const u16* __restrict__ Q,
                                                 const u16* __restrict__ K,
                                                 const u16* __restrict__ Vt,
                                                 u16* __restrict__ AO) {
    __shared__ u16 Qs[8 * 64 * 8];       // [qb 0..7][row 0..63][8]
    __shared__ u16 Ks[8 * 64 * 8];
    __shared__ u16 Vs[8 * 64 * 8];       // [tblk 0..7][dh 0..63][8]
    __shared__ u16 Ps[4][16][88];        // per-wave P, 176B rows (16B-mult, 2-way banks)

    const int tid  = threadIdx.x;
    const int lane = tid & 63, w = tid >> 6;
    const int nl   = lane & 15, q = lane >> 4;
    const int q0 = blockIdx.x * 64;
    const int bh = blockIdx.y, b = bh >> 4, h = bh & 15;
    const size_t kbase = (size_t)bh * Tt * DH;
    const size_t vbase = (size_t)bh * DH * Tt;

    // stage Q tile (rows q0..q0+63), 512 chunks, layout [qb][row][8]
    #pragma unroll
    for (int it = 0; it < 2; ++it) {
        const int c = it * 256 + tid;
        gl2lds16(Q + kbase + (size_t)(q0 + (c & 63)) * DH + (c >> 6) * 8, (char*)Qs + c * 16);
    }

    float m_i[4], l_i[4];
    f32x4 acc_o[4];
    #pragma unroll
    for (int r = 0; r < 4; ++r) { m_i[r] = NEGBIG; l_i[r] = 0.f; }
    #pragma unroll
    for (int nt = 0; nt < 4; ++nt) acc_o[nt] = (f32x4){0.f, 0.f, 0.f, 0.f};

    for (int j0 = 0; j0 <= q0; j0 += 64) {
        __syncthreads();
        #pragma unroll
        for (int it = 0; it < 2; ++it) {
            const int c = it * 256 + tid;
            const int row = c & 63, qb = c >> 6;
            gl2lds16(K  + kbase + (size_t)(j0 + row) * DH + qb * 8, (char*)Ks + c * 16);
            gl2lds16(Vt + vbase + (size_t)row * Tt + j0 + qb * 8,   (char*)Vs + c * 16);
        }
        __syncthreads();

        // S = Q K^T  (16 x 64 per wave)
        f32x4 accs[4];
        #pragma unroll
        for (int nt = 0; nt < 4; ++nt) accs[nt] = (f32x4){0.f, 0.f, 0.f, 0.f};
        #pragma unroll
        for (int s = 0; s < 2; ++s) {
            bf16x8 a = *(const bf16x8*)((const char*)Qs + ((s * 4 + q) * 64 + w * 16 + nl) * 16);
            #pragma unroll
            for (int nt = 0; nt < 4; ++nt) {
                bf16x8 bk = *(const bf16x8*)((const char*)Ks + ((s * 4 + q) * 64 + nt * 16 + nl) * 16);
                accs[nt] = __builtin_amdgcn_mfma_f32_16x16x32_bf16(a, bk, accs[nt], 0, 0, 0);
            }
        }

        // causal mask (diagonal tile only)
        if (j0 == q0) {
            #pragma unroll
            for (int nt = 0; nt < 4; ++nt) {
                const int col = nt * 16 + nl;
                #pragma unroll
                for (int r = 0; r < 4; ++r) {
                    const int rowloc = w * 16 + q * 4 + r;
                    if (col > rowloc) accs[nt][r] = NEGBIG;
                }
            }
        }

        // online softmax (rows owned by this wave; reduce over 16 lanes in quad)
        float alpha[4];
        #pragma unroll
        for (int r = 0; r < 4; ++r) {
            float mx = fmaxf(fmaxf(accs[0][r], accs[1][r]), fmaxf(accs[2][r], accs[3][r]));
            mx = fmaxf(mx, __shfl_xor(mx, 1, 64));
            mx = fmaxf(mx, __shfl_xor(mx, 2, 64));
            mx = fmaxf(mx, __shfl_xor(mx, 4, 64));
            mx = fmaxf(mx, __shfl_xor(mx, 8, 64));
            const float nm = fmaxf(m_i[r], mx);
            alpha[r] = __expf(m_i[r] - nm);
            m_i[r] = nm;
            float rs = 0.f;
            #pragma unroll
            for (int nt = 0; nt < 4; ++nt) {
                const float p = __expf(accs[nt][r] - nm);
                accs[nt][r] = p;
                rs += p;
            }
            rs += __shfl_xor(rs, 1, 64);
            rs += __shfl_xor(rs, 2, 64);
            rs += __shfl_xor(rs, 4, 64);
            rs += __shfl_xor(rs, 8, 64);
            l_i[r] = l_i[r] * alpha[r] + rs;
        }

        // P -> wave-private LDS (C-layout -> A-layout round trip)
        #pragma unroll
        for (int r = 0; r < 4; ++r)
            #pragma unroll
            for (int nt = 0; nt < 4; ++nt)
                Ps[w][q * 4 + r][nt * 16 + nl] = f2bf(accs[nt][r]);

        #pragma unroll
        for (int nt = 0; nt < 4; ++nt)
            #pragma unroll
            for (int r = 0; r < 4; ++r)
                acc_o[nt][r] *= alpha[r];

        // O += P V   (wave-private Ps: no barrier needed; lgkmcnt ordering only)
        #pragma unroll
        for (int s = 0; s < 2; ++s) {
            bf16x8 a = *(const bf16x8*)((const char*)Ps[w] + nl * 176 + s * 64 + q * 16);
            #pragma unroll
            for (int nt = 0; nt < 4; ++nt) {
                bf16x8 bv = *(const bf16x8*)((const char*)Vs + ((s * 4 + q) * 64 + nt * 16 + nl) * 16);
                acc_o[nt] = __builtin_amdgcn_mfma_f32_16x16x32_bf16(a, bv, acc_o[nt], 0, 0, 0);
            }
        }
    }

    // epilogue: AO (B,T,H*DH) bf16
    #pragma unroll
    for (int r = 0; r < 4; ++r) {
        const float inv = 1.0f / l_i[r];
        const int t = q0 + w * 16 + q * 4 + r;
        #pragma unroll
        for (int nt = 0; nt < 4; ++nt) {
            const int dh = nt * 16 + nl;
            AO[((size_t)(b * Tt + t)) * Dd + h * DH + dh] = f2bf(acc_o[nt][r] * inv);
        }
    }
}

// ---------------------------------------------------------------------------
extern "C" void kernel_launch(void* const* d_in, const int* in_sizes, int n_in,
                              void* d_out, int out_size, void* d_ws, size_t ws_size,
                              hipStream_t stream) {
    const float* x_raw    = (const float*)d_in[0];
    // d_in[1] = causal mask (constant tril) — handled analytically, ignored.
    const float* Wqkv_raw = (const float*)d_in[2];
    const float* Wout_raw = (const float*)d_in[3];
    float* out = (float*)d_out;

    const size_t SZ = (size_t)Bb * Hh * Tt * DH;        // 8,388,608
    u16* ws = (u16*)d_ws;
    u16* Qw     = ws;                                   // SZ
    u16* Kw     = ws + SZ;                              // SZ
    u16* Vw     = ws + 2 * SZ;                          // SZ (dead after transpose)
    u16* Vt     = ws + 3 * SZ;                          // SZ
    u16* Wqkv_t = ws + 4 * SZ;                          // 3,145,728  [3072][1024]
    u16* Wout_t = Wqkv_t + (size_t)3 * Dd * Dd;         // 1,048,576  [1024][1024]
    u16* AO     = Vw;                                   // alias V (B,T,D) bf16
    u16* x_b    = (u16*)d_out;                          // x bf16 scratch in d_out

    convert_x<<<dim3(Mrows * Dd / 2048), 256, 0, stream>>>(x_raw, x_b);
    convert_transpose_w<<<dim3(3 * Dd / 64, Dd / 64), 256, 0, stream>>>(Wqkv_raw, Wqkv_t, 3 * Dd, Dd);
    convert_transpose_w<<<dim3(Dd / 64, Dd / 64),     256, 0, stream>>>(Wout_raw, Wout_t, Dd, Dd);

    gemm_mfma<0><<<dim3(3 * Dd / 128, Mrows / 128), 256, 0, stream>>>(x_b, Wqkv_t, Qw, Kw, Vw, nullptr);
    transpose_v<<<dim3(Tt / 64, Bb * Hh), 256, 0, stream>>>(Vw, Vt);
    attn_mfma  <<<dim3(Tt / 64, Bb * Hh), 256, 0, stream>>>(Qw, Kw, Vt, AO);
    gemm_mfma<1><<<dim3(Dd / 128, Mrows / 128), 256, 0, stream>>>(AO, Wout_t, nullptr, nullptr, nullptr, out);
}

// Round 5
// 412.217 us; speedup vs baseline: 9.7018x; 1.1274x over previous
//
#include <hip/hip_runtime.h>
#include <hip/hip_bf16.h>
#include <math.h>

// B=4, T=2048, D=1024, H=16, DH=64.  fp32 in / fp32 out, bf16 MFMA internal.
// out = softmax_causal((xWq)(xWk)^T / 8) (xWv) @ Wout

#define Bb 4
#define Tt 2048
#define Dd 1024
#define Hh 16
#define DH 64
#define Mrows (Bb*Tt)          // 8192
#define NEGBIG (-1.0e30f)

typedef unsigned short u16;
typedef __attribute__((ext_vector_type(8))) short bf16x8;
typedef __attribute__((ext_vector_type(4))) float f32x4;

__device__ __forceinline__ float bf2f(u16 u) {
    union { unsigned int i; float f; } v; v.i = ((unsigned int)u) << 16; return v.f;
}
__device__ __forceinline__ u16 f2bf(float f) {
    union { float f; unsigned int i; } v; v.f = f;
    unsigned int x = v.i;
    return (u16)((x + 0x7fffu + ((x >> 16) & 1u)) >> 16);      // RNE
}

__device__ __forceinline__ float exp2_(float x) {
#if __has_builtin(__builtin_amdgcn_exp2f)
    return __builtin_amdgcn_exp2f(x);      // v_exp_f32: D = 2^S0
#else
    return __expf(x * 0.69314718056f);
#endif
}

typedef __attribute__((address_space(1))) const void glob_cv;
typedef __attribute__((address_space(3))) void lds_v;
__device__ __forceinline__ void gl2lds16(const void* g, void* l) {
    __builtin_amdgcn_global_load_lds((glob_cv*)g, (lds_v*)l, 16, 0, 0);
}

// ---------------------------------------------------------------------------
// fp32 -> bf16 straight convert (x).  8 elems/thread, 16B stores.
// ---------------------------------------------------------------------------
__global__ __launch_bounds__(256) void convert_x(const float* __restrict__ src,
                                                 u16* __restrict__ dst) {
    const long i = ((long)blockIdx.x * 256 + threadIdx.x) * 8;
    float4 f0 = *(const float4*)(src + i);
    float4 f1 = *(const float4*)(src + i + 4);
    union { u16 u[8]; uint4 v; } o;
    o.u[0] = f2bf(f0.x); o.u[1] = f2bf(f0.y); o.u[2] = f2bf(f0.z); o.u[3] = f2bf(f0.w);
    o.u[4] = f2bf(f1.x); o.u[5] = f2bf(f1.y); o.u[6] = f2bf(f1.z); o.u[7] = f2bf(f1.w);
    *(uint4*)(dst + i) = o.v;
}

// ---------------------------------------------------------------------------
// fp32 W[K][N] -> bf16 Wt[N][K]  (transpose via padded LDS tile, coalesced).
// ---------------------------------------------------------------------------
__global__ __launch_bounds__(256) void convert_transpose_w(const float* __restrict__ W,
                                                           u16* __restrict__ Wt,
                                                           int N, int K) {
    __shared__ u16 tile[64][65];
    const int n0 = blockIdx.x * 64, k0 = blockIdx.y * 64;
    const int c = threadIdx.x & 63, r4 = threadIdx.x >> 6;
    #pragma unroll
    for (int p = 0; p < 16; ++p) {
        const int r = p * 4 + r4;
        tile[r][c] = f2bf(W[(size_t)(k0 + r) * N + n0 + c]);
    }
    __syncthreads();
    #pragma unroll
    for (int p = 0; p < 16; ++p) {
        const int r = p * 4 + r4;     // n index
        Wt[(size_t)(n0 + r) * K + k0 + c] = tile[c][r];
    }
}

// ---------------------------------------------------------------------------
// V [bh][t][dh] -> Vt [bh][dh][t]
// ---------------------------------------------------------------------------
__global__ __launch_bounds__(256) void transpose_v(const u16* __restrict__ V,
                                                   u16* __restrict__ Vt) {
    __shared__ u16 tile[64][65];
    const int t0 = blockIdx.x * 64, bh = blockIdx.y;
    const size_t ib = (size_t)bh * Tt * DH, ob = (size_t)bh * DH * Tt;
    const int c = threadIdx.x & 63, r4 = threadIdx.x >> 6;
    #pragma unroll
    for (int p = 0; p < 16; ++p) {
        const int r = p * 4 + r4;
        tile[r][c] = V[ib + (size_t)(t0 + r) * DH + c];
    }
    __syncthreads();
    #pragma unroll
    for (int p = 0; p < 16; ++p) {
        const int r = p * 4 + r4;     // dh
        Vt[ob + (size_t)r * Tt + t0 + c] = tile[c][r];
    }
}

// ---------------------------------------------------------------------------
// MFMA GEMM: C[M][N] = A[M][K] * Bt[N][K]^T, K=1024, BK=32, 128x128 tile,
// 4 waves (2x2), each 4x4 MFMA 16x16x32 tiles.  LDS layout [kblk][row][8].
// MODE 0: scatter to Q(xlog2e/8)/K/V (B,H,T,DH) bf16.  MODE 1: fp32 out.
// ---------------------------------------------------------------------------
template <int MODE>
__global__ __launch_bounds__(256) void gemm_mfma(const u16* __restrict__ A,
                                                 const u16* __restrict__ Bt,
                                                 u16* __restrict__ Qo,
                                                 u16* __restrict__ Ko,
                                                 u16* __restrict__ Vo,
                                                 float* __restrict__ Out) {
    __shared__ u16 As[4 * 128 * 8];      // [qb 0..3][row 0..127][8]
    __shared__ u16 Bs[4 * 128 * 8];
    const int tid  = threadIdx.x;
    const int lane = tid & 63, w = tid >> 6;
    const int ml   = lane & 15, q = lane >> 4;     // fragment row/col & quad
    const int wm   = w >> 1, wn = w & 1;
    const int m0 = blockIdx.y * 128, n0 = blockIdx.x * 128;

    f32x4 acc[4][4];
    #pragma unroll
    for (int i = 0; i < 4; ++i)
        #pragma unroll
        for (int j = 0; j < 4; ++j) acc[i][j] = (f32x4){0.f, 0.f, 0.f, 0.f};

    for (int k0 = 0; k0 < Dd; k0 += 32) {
        __syncthreads();
        #pragma unroll
        for (int it = 0; it < 2; ++it) {
            const int c = it * 256 + tid;          // chunk 0..511
            const int row = c & 127, qb = c >> 7;  // LDS off = c*16
            gl2lds16(A  + (size_t)(m0 + row) * Dd + k0 + qb * 8, (char*)As + c * 16);
            gl2lds16(Bt + (size_t)(n0 + row) * Dd + k0 + qb * 8, (char*)Bs + c * 16);
        }
        __syncthreads();

        bf16x8 af[4], bfr[4];
        #pragma unroll
        for (int i = 0; i < 4; ++i)
            af[i] = *(const bf16x8*)((const char*)As + (q * 128 + wm * 64 + i * 16 + ml) * 16);
        #pragma unroll
        for (int j = 0; j < 4; ++j)
            bfr[j] = *(const bf16x8*)((const char*)Bs + (q * 128 + wn * 64 + j * 16 + ml) * 16);
        #pragma unroll
        for (int i = 0; i < 4; ++i)
            #pragma unroll
            for (int j = 0; j < 4; ++j)
                acc[i][j] = __builtin_amdgcn_mfma_f32_16x16x32_bf16(af[i], bfr[j], acc[i][j], 0, 0, 0);
    }

    // epilogue: C/D layout col=lane&15, row=quad*4+reg
    #pragma unroll
    for (int i = 0; i < 4; ++i) {
        #pragma unroll
        for (int j = 0; j < 4; ++j) {
            #pragma unroll
            for (int r = 0; r < 4; ++r) {
                const int m = m0 + wm * 64 + i * 16 + q * 4 + r;
                const int n = n0 + wn * 64 + j * 16 + ml;
                if (MODE == 0) {
                    const int bb = m >> 11, t = m & 2047;
                    const int s = n >> 10, rem = n & 1023, h = rem >> 6, dh = rem & 63;
                    float v = acc[i][j][r];
                    // Q: fold 1/sqrt(DH) * log2(e) so attention can use v_exp_f32
                    // (base-2) directly; applied in fp32 before bf16 rounding.
                    if (s == 0) v *= 0.125f * 1.44269504089f;
                    u16* dst = (s == 0) ? Qo : (s == 1 ? Ko : Vo);
                    dst[(((size_t)(bb * Hh + h)) * Tt + t) * DH + dh] = f2bf(v);
                } else {
                    Out[(size_t)m * Dd + n] = acc[i][j][r];
                }
            }
        }
    }
}

// ---------------------------------------------------------------------------
// MFMA flash attention, S^T formulation.
// Block: 128 Q-rows, 4 waves; wave owns 32 queries (2 blocks of 16).
// Per 128-key iteration:
//   S^T = K·Q^T   (mfma a=K_frag, b=Q_frag) -> query on lane&15,
//                 keys on (quad, reg, tile)  => softmax stats in registers,
//                 only 2 shuffles (xor16/32) per reduction.
//   P written to wave-private LDS rows [query][key] via packed b64 stores.
//   O^T += V^T·P^T (mfma a=Vt_frag, b=P_frag) -> query stays on lane&15:
//                 alpha rescale and 1/l are in-lane.
// ---------------------------------------------------------------------------
__global__ __launch_bounds__(256) void attn_mfma(const u16* __restrict__ Q,
                                                 const u16* __restrict__ K,
                                                 const u16* __restrict__ Vt,
                                                 u16* __restrict__ AO) {
    __shared__ u16 Qs[8 * 128 * 8];      // [dhb 0..7][qrow 0..127][8]   16 KB
    __shared__ u16 Ks[8 * 128 * 8];      // [dhb 0..7][key  0..127][8]   16 KB
    __shared__ u16 Vs[16 * 64 * 8];      // [kb 0..15][dh 0..63][8]      16 KB
    __shared__ u16 Ps[4][16 * 136];      // per-wave [query 16][128 + 8 pad] 17 KB

    const int tid  = threadIdx.x;
    const int lane = tid & 63, w = tid >> 6;
    const int nl   = lane & 15, q = lane >> 4;
    const int q0 = blockIdx.x * 128;
    const int bh = blockIdx.y, b = bh >> 4, h = bh & 15;
    const size_t kbase = (size_t)bh * Tt * DH;
    const size_t vbase = (size_t)bh * DH * Tt;

    // stage Q tile: 1024 16B chunks, layout [dhb][row][8]
    #pragma unroll
    for (int it = 0; it < 4; ++it) {
        const int c = it * 256 + tid;
        gl2lds16(Q + kbase + (size_t)(q0 + (c & 127)) * DH + (c >> 7) * 8,
                 (char*)Qs + c * 16);
    }

    float m_i[2] = {NEGBIG, NEGBIG};
    float l_i[2] = {0.f, 0.f};
    f32x4 accO[2][4];
    #pragma unroll
    for (int qb = 0; qb < 2; ++qb)
        #pragma unroll
        for (int dt = 0; dt < 4; ++dt) accO[qb][dt] = (f32x4){0.f, 0.f, 0.f, 0.f};

    for (int j0 = 0; j0 <= q0; j0 += 128) {
        __syncthreads();
        #pragma unroll
        for (int it = 0; it < 4; ++it) {
            const int c = it * 256 + tid;
            gl2lds16(K + kbase + (size_t)(j0 + (c & 127)) * DH + (c >> 7) * 8,
                     (char*)Ks + c * 16);
        }
        #pragma unroll
        for (int it = 0; it < 4; ++it) {
            const int c = it * 256 + tid;
            gl2lds16(Vt + vbase + (size_t)(c & 63) * Tt + j0 + (c >> 6) * 8,
                     (char*)Vs + c * 16);
        }
        __syncthreads();

        #pragma unroll
        for (int qb = 0; qb < 2; ++qb) {
            const int qrow = w * 32 + qb * 16 + nl;    // query owned by this lane

            // S^T: per lane holds keys (kt*16 + q*4 + r) for query qrow
            f32x4 accst[8];
            #pragma unroll
            for (int kt = 0; kt < 8; ++kt) accst[kt] = (f32x4){0.f, 0.f, 0.f, 0.f};
            #pragma unroll
            for (int s = 0; s < 2; ++s) {
                bf16x8 bq = *(const bf16x8*)((const char*)Qs +
                        ((s * 4 + q) * 128 + qrow) * 16);
                #pragma unroll
                for (int kt = 0; kt < 8; ++kt) {
                    bf16x8 ak = *(const bf16x8*)((const char*)Ks +
                            ((s * 4 + q) * 128 + kt * 16 + nl) * 16);
                    accst[kt] = __builtin_amdgcn_mfma_f32_16x16x32_bf16(ak, bq, accst[kt], 0, 0, 0);
                }
            }

            // causal mask (diagonal 128-block only)
            if (j0 == q0) {
                #pragma unroll
                for (int kt = 0; kt < 8; ++kt)
                    #pragma unroll
                    for (int r = 0; r < 4; ++r)
                        if (kt * 16 + q * 4 + r > qrow) accst[kt][r] = NEGBIG;
            }

            // stats: in-register reduce over 32 keys + 2 shuffles
            float mx = NEGBIG;
            #pragma unroll
            for (int kt = 0; kt < 8; ++kt) {
                float a0 = fmaxf(accst[kt][0], accst[kt][1]);
                float a1 = fmaxf(accst[kt][2], accst[kt][3]);
                mx = fmaxf(mx, fmaxf(a0, a1));
            }
            mx = fmaxf(mx, __shfl_xor(mx, 16, 64));
            mx = fmaxf(mx, __shfl_xor(mx, 32, 64));
            const float nm    = fmaxf(m_i[qb], mx);
            const float alpha = exp2_(m_i[qb] - nm);
            m_i[qb] = nm;

            float rs = 0.f;
            #pragma unroll
            for (int kt = 0; kt < 8; ++kt) {
                #pragma unroll
                for (int r = 0; r < 4; ++r) {
                    const float p = exp2_(accst[kt][r] - nm);
                    accst[kt][r] = p;
                    rs += p;
                }
            }
            rs += __shfl_xor(rs, 16, 64);
            rs += __shfl_xor(rs, 32, 64);
            l_i[qb] = l_i[qb] * alpha + rs;

            // P -> wave-private LDS row [query nl][keys], packed b64 stores
            #pragma unroll
            for (int kt = 0; kt < 8; ++kt) {
                union { u16 u[4]; uint2 v; } pk;
                #pragma unroll
                for (int r = 0; r < 4; ++r) pk.u[r] = f2bf(accst[kt][r]);
                *(uint2*)((char*)Ps[w] + nl * 272 + kt * 32 + q * 8) = pk.v;
            }

            // rescale O^T (query on lane -> in-lane alpha)
            #pragma unroll
            for (int dt = 0; dt < 4; ++dt) {
                #pragma unroll
                for (int r = 0; r < 4; ++r) accO[qb][dt][r] *= alpha;
            }

            // O^T += V^T · P^T   (a = Vt rows, b = Ps rows)
            #pragma unroll
            for (int s = 0; s < 4; ++s) {
                bf16x8 bp = *(const bf16x8*)((const char*)Ps[w] +
                        nl * 272 + s * 64 + q * 16);
                #pragma unroll
                for (int dt = 0; dt < 4; ++dt) {
                    bf16x8 av = *(const bf16x8*)((const char*)Vs +
                            ((s * 4 + q) * 64 + dt * 16 + nl) * 16);
                    accO[qb][dt] = __builtin_amdgcn_mfma_f32_16x16x32_bf16(av, bp, accO[qb][dt], 0, 0, 0);
                }
            }
        }
    }

    // epilogue: lane holds O^T[dh = dt*16+q*4+r][query = qrow]; 1/l in-lane.
    #pragma unroll
    for (int qb = 0; qb < 2; ++qb) {
        const float inv = 1.0f / l_i[qb];
        const int t = q0 + w * 32 + qb * 16 + nl;
        #pragma unroll
        for (int dt = 0; dt < 4; ++dt) {
            union { u16 u[4]; uint2 v; } pk;
            #pragma unroll
            for (int r = 0; r < 4; ++r) pk.u[r] = f2bf(accO[qb][dt][r] * inv);
            *(uint2*)(AO + ((size_t)(b * Tt + t)) * Dd + h * DH + dt * 16 + q * 4) = pk.v;
        }
    }
}

// ---------------------------------------------------------------------------
extern "C" void kernel_launch(void* const* d_in, const int* in_sizes, int n_in,
                              void* d_out, int out_size, void* d_ws, size_t ws_size,
                              hipStream_t stream) {
    const float* x_raw    = (const float*)d_in[0];
    // d_in[1] = causal mask (constant tril) — handled analytically, ignored.
    const float* Wqkv_raw = (const float*)d_in[2];
    const float* Wout_raw = (const float*)d_in[3];
    float* out = (float*)d_out;

    const size_t SZ = (size_t)Bb * Hh * Tt * DH;        // 8,388,608
    u16* ws = (u16*)d_ws;
    u16* Qw     = ws;                                   // SZ
    u16* Kw     = ws + SZ;                              // SZ
    u16* Vw     = ws + 2 * SZ;                          // SZ (dead after transpose)
    u16* Vt     = ws + 3 * SZ;                          // SZ
    u16* Wqkv_t = ws + 4 * SZ;                          // 3,145,728  [3072][1024]
    u16* Wout_t = Wqkv_t + (size_t)3 * Dd * Dd;         // 1,048,576  [1024][1024]
    u16* AO     = Vw;                                   // alias V (B,T,D) bf16
    u16* x_b    = (u16*)d_out;                          // x bf16 scratch in d_out

    convert_x<<<dim3(Mrows * Dd / 2048), 256, 0, stream>>>(x_raw, x_b);
    convert_transpose_w<<<dim3(3 * Dd / 64, Dd / 64), 256, 0, stream>>>(Wqkv_raw, Wqkv_t, 3 * Dd, Dd);
    convert_transpose_w<<<dim3(Dd / 64, Dd / 64),     256, 0, stream>>>(Wout_raw, Wout_t, Dd, Dd);

    gemm_mfma<0><<<dim3(3 * Dd / 128, Mrows / 128), 256, 0, stream>>>(x_b, Wqkv_t, Qw, Kw, Vw, nullptr);
    transpose_v<<<dim3(Tt / 64, Bb * Hh), 256, 0, stream>>>(Vw, Vt);
    attn_mfma  <<<dim3(Tt / 128, Bb * Hh), 256, 0, stream>>>(Qw, Kw, Vt, AO);
    gemm_mfma<1><<<dim3(Dd / 128, Mrows / 128), 256, 0, stream>>>(AO, Wout_t, nullptr, nullptr, nullptr, out);
}